// Round 15
// baseline (109.388 us; speedup 1.0000x reference)
//
#include <hip/hip_runtime.h>

typedef __attribute__((ext_vector_type(8))) short short8v;
typedef __attribute__((ext_vector_type(4))) float f32x4;
typedef __attribute__((ext_vector_type(2))) float f32x2;
typedef __attribute__((ext_vector_type(4))) unsigned int u32x4;

constexpr int Bsz = 4;
constexpr int Hh = 64, Wwd = 64;
constexpr int HWp = Hh * Wwd;            // 4096
constexpr int NPIX = Bsz * HWp;          // 16384
constexpr int HH = 66;                   // halo dim
constexpr int HPIX = HH * HH;            // 4356
constexpr int Kdim = 2304;               // 9*256
constexpr int NSTEP = 36;                // Kdim / 64

// ---- workspace byte offsets
constexpr size_t B_H1H  = 0;
constexpr size_t HALO_BYTES = (size_t)Bsz * HPIX * 256 * 2;      // 8,921,088
constexpr size_t B_H2H  = B_H1H + HALO_BYTES;
constexpr size_t B_XTH  = B_H2H + HALO_BYTES;
constexpr size_t B_PROD = B_XTH + HALO_BYTES;
constexpr size_t B_OFFP = B_PROD + (size_t)NPIX * 4;
constexpr size_t B_WB2  = B_OFFP + (size_t)NPIX * 32 * 4;        // frag-packed (32-o tiles)
constexpr size_t B_WBD  = B_WB2 + (size_t)256 * Kdim * 2;        // frag-packed (32-o tiles)
constexpr size_t B_WB3  = B_WBD + (size_t)256 * Kdim * 2;        // frag-packed (one 32-o tile)
constexpr size_t B_PARTB = B_WB3 + (size_t)73728 * 2;            // 16.8 MB fp32 partial (kb=1)
// partial A (kb=0) reuses ws[0 .. 17.8MB) = h1h+h2h region (dead after conv3g)

static __device__ __forceinline__ unsigned short f2bf(float f) {
    unsigned u = __builtin_bit_cast(unsigned, f);
    u += 0x7FFFu + ((u >> 16) & 1u);
    return (unsigned short)(u >> 16);
}
static __device__ __forceinline__ unsigned cvt_pk_bf16(float lo, float hi) {
    unsigned r;
    asm("v_cvt_pk_bf16_f32 %0, %1, %2" : "=v"(r) : "v"(lo), "v"(hi));
    return r;
}
static __device__ __forceinline__ f32x2 pk_mul(f32x2 a, f32x2 b) {
    f32x2 d;
    asm("v_pk_mul_f32 %0, %1, %2" : "=v"(d) : "v"(a), "v"(b));
    return d;
}
static __device__ __forceinline__ f32x2 pk_fma(f32x2 a, f32x2 b, f32x2 c) {
    f32x2 d;
    asm("v_pk_fma_f32 %0, %1, %2, %3" : "=v"(d) : "v"(a), "v"(b), "v"(c));
    return d;
}
static __device__ __forceinline__ f32x2 unpack2(unsigned u) {
    f32x2 v;
    v.x = __builtin_bit_cast(float, u << 16);
    v.y = __builtin_bit_cast(float, u & 0xFFFF0000u);
    return v;
}
static __device__ __forceinline__ int swz(int u) {
    return (((u & 7) ^ ((u >> 3) & 7)) << 3);
}

// ---------------------------------------------------------------- zero halo rings + prod
__global__ void k_zero_ring(unsigned short* h1h, unsigned short* h2h, unsigned short* xth,
                            float* prod) {
    int blk = blockIdx.x;
    if (blk >= 3120) {
        unsigned* p = (unsigned*)prod + (size_t)(blk - 3120) * 128 + threadIdx.x;
        *p = 0;
        return;
    }
    int img = blk / 260;
    int rp = blk - img * 260;
    int buf = img >> 2, b = img & 3;
    int y, x;
    if (rp < 66) { y = 0; x = rp; }
    else if (rp < 132) { y = 65; x = rp - 66; }
    else { int s2 = rp - 132; y = 1 + (s2 >> 1); x = (s2 & 1) * 65; }
    unsigned short* base = (buf == 0) ? h1h : (buf == 1) ? h2h : xth;
    unsigned* p = (unsigned*)(base + ((size_t)b * HPIX + y * HH + x) * 256);
    p[threadIdx.x] = 0;
}

// ---------------------------------------------------------------- fused: x_ref->xth transpose + prod partial
__global__ void k_prodx(const float* __restrict__ xr, const float* __restrict__ xn,
                        unsigned short* __restrict__ xth, float* __restrict__ prod) {
    __shared__ float t[32][33];
    __shared__ float red[8][33];
    int b = blockIdx.z;
    int c0 = blockIdx.y * 32;
    int y = blockIdx.x >> 1, x0 = (blockIdx.x & 1) * 32;
    int tx = threadIdx.x, ty = threadIdx.y;
    float part = 0.f;
#pragma unroll
    for (int i = 0; i < 32; i += 8) {
        size_t idx = ((size_t)b * 256 + c0 + ty + i) * HWp + y * Wwd + x0 + tx;
        float vr = xr[idx];
        float vn = xn[idx];
        t[ty + i][tx] = vr;
        part = fmaf(vr, vn, part);
    }
    red[ty][tx] = part;
    __syncthreads();
#pragma unroll
    for (int i = 0; i < 32; i += 8)
        xth[((size_t)b * HPIX + (y + 1) * HH + (x0 + ty + i + 1)) * 256 + c0 + tx] =
            f2bf(t[tx][ty + i]);
    if (ty == 0) {
        float s = red[0][tx] + red[1][tx] + red[2][tx] + red[3][tx] +
                  red[4][tx] + red[5][tx] + red[6][tx] + red[7][tx];
        atomicAdd(&prod[b * HWp + y * Wwd + x0 + tx], s);
    }
}

// ---------------------------------------------------------------- fused: corr (box3x3+leaky) + conv1 -> h1h
__global__ __launch_bounds__(256) void k_conv1c(const float* __restrict__ prod,
                                                const float* __restrict__ w1,
                                                const float* __restrict__ b1,
                                                unsigned short* __restrict__ h1h) {
    __shared__ float pp[5][36];
    __shared__ float pt[3][34];
    int px0 = blockIdx.x * 32;
    int b = px0 >> 12, y = (px0 & 4095) >> 6, x0 = px0 & 63;
    int tid = threadIdx.x;
    if (tid < 180) {
        int i = tid / 36, j = tid - i * 36;
        int yy = y - 2 + i, xx = x0 - 2 + j;
        float v = 0.f;
        if (yy >= 0 && yy < Hh && xx >= 0 && xx < Wwd) v = prod[b * HWp + yy * Wwd + xx];
        pp[i][j] = v;
    }
    __syncthreads();
    if (tid < 102) {
        int i = tid / 34, j = tid - i * 34;
        int yy = y - 1 + i, xx = x0 - 1 + j;
        float v = 0.f;
        if (yy >= 0 && yy < Hh && xx >= 0 && xx < Wwd) {
            float s = pp[i][j]     + pp[i][j + 1]     + pp[i][j + 2] +
                      pp[i + 1][j] + pp[i + 1][j + 1] + pp[i + 1][j + 2] +
                      pp[i + 2][j] + pp[i + 2][j + 1] + pp[i + 2][j + 2];
            s *= (1.0f / 256.0f);
            v = (s > 0.f) ? s : 0.1f * s;
        }
        pt[i][j] = v;
    }
    float wl[9];
#pragma unroll
    for (int k = 0; k < 9; ++k) wl[k] = w1[tid * 9 + k];
    float bias = b1[tid];
    __syncthreads();
    for (int p = 0; p < 32; ++p) {
        float acc = bias;
#pragma unroll
        for (int ky = 0; ky < 3; ++ky)
#pragma unroll
            for (int kx = 0; kx < 3; ++kx) acc = fmaf(pt[ky][p + kx], wl[ky * 3 + kx], acc);
        acc = fmaxf(acc, 0.f);
        h1h[((size_t)b * HPIX + (y + 1) * HH + (x0 + p + 1)) * 256 + tid] = f2bf(acc);
    }
}

// ---------------------------------------------------------------- all weight packs
__global__ void k_packall(const float* __restrict__ w2, const float* __restrict__ wd,
                          const float* __restrict__ w3,
                          unsigned short* __restrict__ wb2f, unsigned short* __restrict__ wbdf,
                          unsigned short* __restrict__ wb3f) {
    int blk = blockIdx.x;
    if (blk < 4608) {
        const float* w = (blk < 2304) ? w2 : wd;
        unsigned short* out = (blk < 2304) ? wb2f : wbdf;
        int i = (blk % 2304) * 256 + threadIdx.x;
        int e = i & 7;
        int lane = (i >> 3) & 63;
        int mi = (i >> 9) & 1;
        int kf = (i >> 10) & 1;
        int rest = i >> 11;                           // [0,288)
        int s = rest % 36;
        int wv = rest / 36;
        int o = wv * 32 + mi * 16 + (lane & 15);
        int kk = s * 64 + (kf * 4 + (lane >> 4)) * 8 + e;
        int c = kk & 255, tap = kk >> 8;
        out[i] = f2bf(w[((size_t)o * 256 + c) * 9 + tap]);
    } else {
        int i = (blk - 4608) * 256 + threadIdx.x;
        int e = i & 7;
        int lane = (i >> 3) & 63;
        int oi = (i >> 9) & 1;
        int kf = (i >> 10) & 1;
        int s = i >> 11;                              // [0,36)
        int o = oi * 16 + (lane & 15);
        int kk = s * 64 + (kf * 4 + (lane >> 4)) * 8 + e;
        int c = kk & 255, tap = kk >> 8;
        float v = (o < 18) ? w3[((size_t)o * 256 + c) * 9 + tap] : 0.f;
        wb3f[i] = f2bf(v);
    }
}

// ---------------------------------------------------------------- conv2 GEMM: 64px x 128o, 4 waves, 2 blocks/CU, ITER2
__global__ __launch_bounds__(256) void k_conv2g(const unsigned short* __restrict__ h1h,
                                                const unsigned short* __restrict__ wbf,
                                                const float* __restrict__ bias,
                                                unsigned short* __restrict__ h2h) {
    __shared__ short S_s[4][64 * 64];                 // 4 bufs, 32 KB
    const int tid = threadIdx.x;
    const int bid = blockIdx.x;
    const int lin = (bid & 7) * 64 + (bid >> 3);      // XCD-bijective, 512 blocks
    const int px0 = (lin >> 1) * 64;
    const int oblk = lin & 1;
    const int b = px0 >> 12;
    const unsigned short* hb = h1h + (size_t)b * HPIX * 256;
    const int pxl = tid >> 2;
    const int px = px0 + pxl;
    const int y = (px & 4095) >> 6, x = px & 63;
    const int u0 = (tid & 3) * 2;
    const int lane = tid & 63, wv = tid >> 6;
    const int ot = oblk * 4 + wv;                      // global 32-o tile
    const unsigned short* wfb = wbf + (size_t)ot * NSTEP * 2048 + lane * 8;
    const unsigned short* abase0 = hb + (size_t)((y + 1) * HH + (x + 1)) * 256 + u0 * 8;

    f32x4 acc[4][2] = {};
    u32x4 wA[2][4], wB[2][4];
    u32x4 aP[4], aQ[4];
    float bia[2];
#pragma unroll
    for (int oi = 0; oi < 2; ++oi) bia[oi] = bias[ot * 32 + oi * 16 + (lane & 15)];

    const int wr0 = pxl * 64 + ((u0 ^ (pxl & 7)) << 3);
    const int wr1 = pxl * 64 + (((u0 + 1) ^ (pxl & 7)) << 3);

    auto WLOAD = [&](int s, u32x4 (&wreg)[4]) {
#pragma unroll
        for (int f = 0; f < 4; ++f)
            wreg[f] = *(const u32x4*)(wfb + ((size_t)s * 4 + f) * 512);
    };
    auto ALOAD = [&](int s, u32x4& a0, u32x4& a1) {
        int tap = s >> 2, chunk = s & 3;
        int aoff = ((tap / 3 - 1) * HH + (tap % 3 - 1)) * 256 + chunk * 64;
        a0 = *(const u32x4*)(abase0 + aoff);
        a1 = *(const u32x4*)(abase0 + aoff + 8);
    };

    {
        u32x4 a0, a1, a2, a3;
        ALOAD(0, a0, a1);
        ALOAD(1, a2, a3);
        WLOAD(0, wA[0]);
        WLOAD(1, wA[1]);
        *(u32x4*)&S_s[0][wr0] = a0;
        *(u32x4*)&S_s[0][wr1] = a1;
        *(u32x4*)&S_s[1][wr0] = a2;
        *(u32x4*)&S_s[1][wr1] = a3;
        ALOAD(2, aP[0], aP[1]);
        ALOAD(3, aP[2], aP[3]);
        asm volatile("s_waitcnt lgkmcnt(0)" ::: "memory");
    }

    auto ITER2 = [&](int s, u32x4 (&wcur)[2][4], u32x4 (&wnxt)[2][4],
                     u32x4 (&aC)[4], u32x4 (&aN)[4], short* SBc, short* SBn) {
        __builtin_amdgcn_s_barrier();
        __builtin_amdgcn_sched_barrier(0);
        if (s + 2 < NSTEP) {
            *(u32x4*)&SBn[wr0] = aC[0];
            *(u32x4*)&SBn[wr1] = aC[1];
            *(u32x4*)&SBn[64 * 64 + wr0] = aC[2];
            *(u32x4*)&SBn[64 * 64 + wr1] = aC[3];
        }
        if (s + 4 < NSTEP) {
            ALOAD(s + 4, aN[0], aN[1]);
            ALOAD(s + 5, aN[2], aN[3]);
        }
        if (s + 2 < NSTEP) {
            WLOAD(s + 2, wnxt[0]);
            WLOAD(s + 3, wnxt[1]);
        }
#pragma unroll
        for (int half = 0; half < 2; ++half) {
            const short* SB = SBc + half * 64 * 64;
            short8v af[4][2];
#pragma unroll
            for (int pi = 0; pi < 4; ++pi) {
                int row = pi * 16 + (lane & 15);
#pragma unroll
                for (int kf = 0; kf < 2; ++kf) {
                    int c8 = kf * 4 + (lane >> 4);
                    af[pi][kf] = *(const short8v*)&SB[row * 64 + ((c8 ^ (row & 7)) << 3)];
                }
            }
            __builtin_amdgcn_s_setprio(1);
#pragma unroll
            for (int kf = 0; kf < 2; ++kf)
#pragma unroll
                for (int pi = 0; pi < 4; ++pi)
#pragma unroll
                    for (int oi = 0; oi < 2; ++oi)
                        acc[pi][oi] = __builtin_amdgcn_mfma_f32_16x16x32_bf16(
                            af[pi][kf], __builtin_bit_cast(short8v, wcur[half][kf * 2 + oi]),
                            acc[pi][oi], 0, 0, 0);
            __builtin_amdgcn_s_setprio(0);
        }
        asm volatile("s_waitcnt lgkmcnt(0)" ::: "memory");
    };

    for (int s4 = 0; s4 < NSTEP; s4 += 4) {
        ITER2(s4, wA, wB, aP, aQ, &S_s[0][0], &S_s[2][0]);
        ITER2(s4 + 2, wB, wA, aQ, aP, &S_s[2][0], &S_s[0][0]);
    }

#pragma unroll
    for (int pi = 0; pi < 4; ++pi) {
#pragma unroll
        for (int j = 0; j < 4; ++j) {
            int p2 = px0 + pi * 16 + (lane >> 4) * 4 + j;
            int yy = (p2 & 4095) >> 6, xx = p2 & 63;
            unsigned short* dst = h2h + ((size_t)b * HPIX + (yy + 1) * HH + (xx + 1)) * 256;
#pragma unroll
            for (int oi = 0; oi < 2; ++oi) {
                int o = ot * 32 + oi * 16 + (lane & 15);
                dst[o] = f2bf(fmaxf(acc[pi][oi][j] + bia[oi], 0.f));
            }
        }
    }
}

// ---------------------------------------------------------------- conv3 GEMM: 64px x 32o, 4 waves (16px each), ITER2
__global__ __launch_bounds__(256) void k_conv3g(const unsigned short* __restrict__ h2h,
                                                const unsigned short* __restrict__ wb3f,
                                                const float* __restrict__ bias,
                                                float* __restrict__ offp) {
    __shared__ short S_s[4][64 * 64];                 // 4 bufs, 32 KB
    const int tid = threadIdx.x;
    const int bid = blockIdx.x;
    const int px0 = ((bid & 7) * 32 + (bid >> 3)) * 64;   // XCD-bijective, 256 blocks
    const int b = px0 >> 12;
    const unsigned short* hb = h2h + (size_t)b * HPIX * 256;
    const int pxl = tid >> 2;
    const int px = px0 + pxl;
    const int y = (px & 4095) >> 6, x = px & 63;
    const int u0 = (tid & 3) * 2;
    const int lane = tid & 63, wv = tid >> 6;
    const unsigned short* wfb = wb3f + lane * 8;
    const unsigned short* abase0 = hb + (size_t)((y + 1) * HH + (x + 1)) * 256 + u0 * 8;

    f32x4 acc[2] = {};
    u32x4 wA[2][4], wB[2][4];
    u32x4 aP[4], aQ[4];
    float bia[2];
#pragma unroll
    for (int oi = 0; oi < 2; ++oi) {
        int o = oi * 16 + (lane & 15);
        bia[oi] = (o < 18) ? bias[o] : 0.f;
    }

    const int wr0 = pxl * 64 + ((u0 ^ (pxl & 7)) << 3);
    const int wr1 = pxl * 64 + (((u0 + 1) ^ (pxl & 7)) << 3);

    auto WLOAD = [&](int s, u32x4 (&wreg)[4]) {
#pragma unroll
        for (int f = 0; f < 4; ++f)
            wreg[f] = *(const u32x4*)(wfb + ((size_t)s * 4 + f) * 512);
    };
    auto ALOAD = [&](int s, u32x4& a0, u32x4& a1) {
        int tap = s >> 2, chunk = s & 3;
        int aoff = ((tap / 3 - 1) * HH + (tap % 3 - 1)) * 256 + chunk * 64;
        a0 = *(const u32x4*)(abase0 + aoff);
        a1 = *(const u32x4*)(abase0 + aoff + 8);
    };

    {
        u32x4 a0, a1, a2, a3;
        ALOAD(0, a0, a1);
        ALOAD(1, a2, a3);
        WLOAD(0, wA[0]);
        WLOAD(1, wA[1]);
        *(u32x4*)&S_s[0][wr0] = a0;
        *(u32x4*)&S_s[0][wr1] = a1;
        *(u32x4*)&S_s[1][wr0] = a2;
        *(u32x4*)&S_s[1][wr1] = a3;
        ALOAD(2, aP[0], aP[1]);
        ALOAD(3, aP[2], aP[3]);
        asm volatile("s_waitcnt lgkmcnt(0)" ::: "memory");
    }

    auto ITER2 = [&](int s, u32x4 (&wcur)[2][4], u32x4 (&wnxt)[2][4],
                     u32x4 (&aC)[4], u32x4 (&aN)[4], short* SBc, short* SBn) {
        __builtin_amdgcn_s_barrier();
        __builtin_amdgcn_sched_barrier(0);
        if (s + 2 < NSTEP) {
            *(u32x4*)&SBn[wr0] = aC[0];
            *(u32x4*)&SBn[wr1] = aC[1];
            *(u32x4*)&SBn[64 * 64 + wr0] = aC[2];
            *(u32x4*)&SBn[64 * 64 + wr1] = aC[3];
        }
        if (s + 4 < NSTEP) {
            ALOAD(s + 4, aN[0], aN[1]);
            ALOAD(s + 5, aN[2], aN[3]);
        }
        if (s + 2 < NSTEP) {
            WLOAD(s + 2, wnxt[0]);
            WLOAD(s + 3, wnxt[1]);
        }
#pragma unroll
        for (int half = 0; half < 2; ++half) {
            const short* SB = SBc + half * 64 * 64;
            short8v af[2];
#pragma unroll
            for (int kf = 0; kf < 2; ++kf) {
                int row = wv * 16 + (lane & 15);
                int c8 = kf * 4 + (lane >> 4);
                af[kf] = *(const short8v*)&SB[row * 64 + ((c8 ^ (row & 7)) << 3)];
            }
            __builtin_amdgcn_s_setprio(1);
#pragma unroll
            for (int kf = 0; kf < 2; ++kf)
#pragma unroll
                for (int oi = 0; oi < 2; ++oi)
                    acc[oi] = __builtin_amdgcn_mfma_f32_16x16x32_bf16(
                        af[kf], __builtin_bit_cast(short8v, wcur[half][kf * 2 + oi]),
                        acc[oi], 0, 0, 0);
            __builtin_amdgcn_s_setprio(0);
        }
        asm volatile("s_waitcnt lgkmcnt(0)" ::: "memory");
    };

    for (int s4 = 0; s4 < NSTEP; s4 += 4) {
        ITER2(s4, wA, wB, aP, aQ, &S_s[0][0], &S_s[2][0]);
        ITER2(s4 + 2, wB, wA, aQ, aP, &S_s[2][0], &S_s[0][0]);
    }

#pragma unroll
    for (int j = 0; j < 4; ++j) {
        int p2 = px0 + wv * 16 + (lane >> 4) * 4 + j;
#pragma unroll
        for (int oi = 0; oi < 2; ++oi) {
            int o = oi * 16 + (lane & 15);
            offp[(size_t)p2 * 32 + o] = fmaxf(acc[oi][j] + bia[oi], 0.f);
        }
    }
}

// ---------------------------------------------------------------- dcn GEMM split-K: 64px x 256o x K/2, 8 waves, ITER2
// grid 512: lin>>1 = px-tile, lin&1 = kb (taps [kb*4.5, ..)). 2 blocks/CU, independent barrier domains.
__global__ __launch_bounds__(512) void k_dcng(const unsigned short* __restrict__ xth,
                                              const float* __restrict__ offp,
                                              const unsigned short* __restrict__ wbf,
                                              float* __restrict__ partA,
                                              float* __restrict__ partB) {
    __shared__ short S_s[4][64 * 64];                 // 4 bufs, 32 KB
    const int tid = threadIdx.x;
    const int bid = blockIdx.x;
    const int lin = (bid & 7) * 64 + (bid >> 3);      // XCD-bijective, 512 blocks
    const int px0 = (lin >> 1) * 64;
    const int kb = lin & 1;
    const int S0 = kb * 18, SEND = S0 + 18;
    float* part = kb ? partB : partA;
    const int b = px0 >> 12;
    const unsigned short* xb = xth + (size_t)b * HPIX * 256;
    const int pxl = tid >> 3;
    const int px = px0 + pxl;
    const int y = (px & 4095) >> 6, x = px & 63;
    const int u0 = tid & 7;
    const int lane = tid & 63, wv = tid >> 6;
    const unsigned short* wfb = wbf + (size_t)wv * NSTEP * 2048 + lane * 8;
    const float2* offv = (const float2*)offp;

    f32x4 acc[2][4] = {};
    u32x4 wA[2][4], wB[2][4];
    u32x4 g[2][4];
    const int wr0 = pxl * 64 + ((u0 ^ (pxl & 7)) << 3);

    const unsigned short* pcorner[4];
    f32x2 wpair[4];
    float2 offn;

    auto SETUP = [&](int tap, float dyo, float dxo) {
        int ky = tap / 3 - 1, kx = tap % 3 - 1;
        float ypos = (float)(y + ky) + dyo;
        float xpos = (float)(x + kx) + dxo;
        float y0f = floorf(ypos), x0f = floorf(xpos);
        float wy = ypos - y0f, wx = xpos - x0f;
        int y0 = (int)y0f, x0 = (int)x0f;
        bool y0v = (y0 >= 0) && (y0 < Hh), y1v = (y0 + 1 >= 0) && (y0 + 1 < Hh);
        bool x0v = (x0 >= 0) && (x0 < Wwd), x1v = (x0 + 1 >= 0) && (x0 + 1 < Wwd);
        int hy0 = min(max(y0, -1), 64) + 1, hy1 = min(max(y0 + 1, -1), 64) + 1;
        int hx0 = min(max(x0, -1), 64) + 1, hx1 = min(max(x0 + 1, -1), 64) + 1;
        float w0 = (1.f - wy) * (1.f - wx) * (float)(y0v && x0v);
        float w1 = (1.f - wy) * wx * (float)(y0v && x1v);
        float w2 = wy * (1.f - wx) * (float)(y1v && x0v);
        float w3 = wy * wx * (float)(y1v && x1v);
        wpair[0] = (f32x2){w0, w0};
        wpair[1] = (f32x2){w1, w1};
        wpair[2] = (f32x2){w2, w2};
        wpair[3] = (f32x2){w3, w3};
        pcorner[0] = xb + (size_t)((hy0 * HH + hx0) * 256) + u0 * 8;
        pcorner[1] = xb + (size_t)((hy0 * HH + hx1) * 256) + u0 * 8;
        pcorner[2] = xb + (size_t)((hy1 * HH + hx0) * 256) + u0 * 8;
        pcorner[3] = xb + (size_t)((hy1 * HH + hx1) * 256) + u0 * 8;
    };
    auto WLOAD = [&](int s, u32x4 (&wreg)[4]) {
#pragma unroll
        for (int f = 0; f < 4; ++f)
            wreg[f] = *(const u32x4*)(wfb + ((size_t)s * 4 + f) * 512);
    };
    auto GISSUE = [&](int s, u32x4 (&gr)[4]) {
        const int nco = (s & 3) * 64;
#pragma unroll
        for (int c = 0; c < 4; ++c) gr[c] = *(const u32x4*)(pcorner[c] + nco);
    };
    auto COMBINE_WRITE = [&](u32x4 (&gr)[4], short* SBn) {
        u32x4 res;
#pragma unroll
        for (int qd = 0; qd < 4; ++qd) {
            f32x2 a = pk_mul(unpack2(gr[0][qd]), wpair[0]);
            a = pk_fma(unpack2(gr[1][qd]), wpair[1], a);
            a = pk_fma(unpack2(gr[2][qd]), wpair[2], a);
            a = pk_fma(unpack2(gr[3][qd]), wpair[3], a);
            res[qd] = cvt_pk_bf16(a.x, a.y);
        }
        *(u32x4*)&SBn[wr0] = res;
    };

    // prologue (generic in S0): invariant entering ITER2(s): wpair = tap((s+2)>>2), g = gathers(s+2,s+3)
    {
        int tap0 = S0 >> 2;
        float2 o0 = offv[(size_t)px * 16 + tap0];
        SETUP(tap0, o0.x, o0.y);
        u32x4 g0[4], g1[4];
        GISSUE(S0, g0);
        GISSUE(S0 + 1, g1);
        WLOAD(S0, wA[0]);
        WLOAD(S0 + 1, wA[1]);
        COMBINE_WRITE(g0, &S_s[0][0]);
        COMBINE_WRITE(g1, &S_s[1][0]);
        if ((S0 & 3) == 2) {                          // steps S0+2,S0+3 start a new tap
            float2 o1 = offv[(size_t)px * 16 + tap0 + 1];
            SETUP(tap0 + 1, o1.x, o1.y);
        }
        GISSUE(S0 + 2, g[0]);
        GISSUE(S0 + 3, g[1]);
        int tn = (S0 >> 2) + 1;
        offn = offv[(size_t)px * 16 + (tn <= 8 ? tn : 8)];
        asm volatile("s_waitcnt lgkmcnt(0)" ::: "memory");
    }

    auto ITER2 = [&](int s, u32x4 (&wcur)[2][4], u32x4 (&wnxt)[2][4], short* SBc, short* SBn) {
        __builtin_amdgcn_s_barrier();
        __builtin_amdgcn_sched_barrier(0);
        if (s + 2 < SEND) {
            COMBINE_WRITE(g[0], SBn);
            COMBINE_WRITE(g[1], SBn + 64 * 64);
        }
        if ((s & 3) == 0 && s + 4 < SEND)
            SETUP((s + 4) >> 2, offn.x, offn.y);
        if ((s & 3) == 2 && ((s + 8) >> 2) < 9)
            offn = offv[(size_t)px * 16 + ((s + 8) >> 2)];
        if (s + 4 < SEND) {
            GISSUE(s + 4, g[0]);
            GISSUE(s + 5, g[1]);
        }
        if (s + 2 < SEND) {
            WLOAD(s + 2, wnxt[0]);
            WLOAD(s + 3, wnxt[1]);
        }
#pragma unroll
        for (int half = 0; half < 2; ++half) {
            const short* SB = SBc + half * 64 * 64;
            short8v sf[4][2];
#pragma unroll
            for (int ni = 0; ni < 4; ++ni) {
                int row = ni * 16 + (lane & 15);
#pragma unroll
                for (int kf = 0; kf < 2; ++kf) {
                    int c8 = kf * 4 + (lane >> 4);
                    sf[ni][kf] = *(const short8v*)&SB[row * 64 + ((c8 ^ (row & 7)) << 3)];
                }
            }
            __builtin_amdgcn_s_setprio(1);
#pragma unroll
            for (int kf = 0; kf < 2; ++kf)
#pragma unroll
                for (int mi = 0; mi < 2; ++mi)
#pragma unroll
                    for (int ni = 0; ni < 4; ++ni)
                        acc[mi][ni] = __builtin_amdgcn_mfma_f32_16x16x32_bf16(
                            __builtin_bit_cast(short8v, wcur[half][kf * 2 + mi]), sf[ni][kf],
                            acc[mi][ni], 0, 0, 0);
            __builtin_amdgcn_s_setprio(0);
        }
        asm volatile("s_waitcnt lgkmcnt(0)" ::: "memory");
    };

    // 9 ITER2: 4 pairs + 1 tail
    for (int s4 = S0; s4 < S0 + 16; s4 += 4) {
        ITER2(s4, wA, wB, &S_s[0][0], &S_s[2][0]);
        ITER2(s4 + 2, wB, wA, &S_s[2][0], &S_s[0][0]);
    }
    ITER2(S0 + 16, wA, wB, &S_s[0][0], &S_s[2][0]);

#pragma unroll
    for (int mi = 0; mi < 2; ++mi) {
        int o = wv * 32 + mi * 16 + (lane >> 4) * 4;
#pragma unroll
        for (int j = 0; j < 4; ++j) {
            size_t rowbase = ((size_t)b * 256 + o + j) * HWp;
#pragma unroll
            for (int ni = 0; ni < 4; ++ni) {
                int p2 = (px0 + ni * 16 + (lane & 15)) & 4095;
                part[rowbase + p2] = acc[mi][ni][j];
            }
        }
    }
}

// ---------------------------------------------------------------- combine: out = 0.5*(xn + relu(pA+pB))
__global__ void k_comb(const float* __restrict__ pA, const float* __restrict__ pB,
                       const float* __restrict__ xn, float* __restrict__ out) {
    int i = blockIdx.x * 256 + threadIdx.x;           // f32x4 index, 1,048,576 total
    f32x4 a = ((const f32x4*)pA)[i];
    f32x4 bb = ((const f32x4*)pB)[i];
    f32x4 n = ((const f32x4*)xn)[i];
    f32x4 r;
#pragma unroll
    for (int j = 0; j < 4; ++j)
        r[j] = 0.5f * (n[j] + fmaxf(a[j] + bb[j], 0.f));
    ((f32x4*)out)[i] = r;
}

extern "C" void kernel_launch(void* const* d_in, const int* in_sizes, int n_in,
                              void* d_out, int out_size, void* d_ws, size_t ws_size,
                              hipStream_t stream) {
    const float* x_ref  = (const float*)d_in[0];
    const float* x_next = (const float*)d_in[1];
    const float* w1 = (const float*)d_in[2];
    const float* b1 = (const float*)d_in[3];
    const float* w2 = (const float*)d_in[4];
    const float* b2 = (const float*)d_in[5];
    const float* w3 = (const float*)d_in[6];
    const float* b3 = (const float*)d_in[7];
    const float* wd = (const float*)d_in[8];
    float* out = (float*)d_out;
    char* ws = (char*)d_ws;

    unsigned short* h1h = (unsigned short*)(ws + B_H1H);
    unsigned short* h2h = (unsigned short*)(ws + B_H2H);
    unsigned short* xth = (unsigned short*)(ws + B_XTH);
    float* prod = (float*)(ws + B_PROD);
    float* offp = (float*)(ws + B_OFFP);
    unsigned short* wb2f = (unsigned short*)(ws + B_WB2);
    unsigned short* wbdf = (unsigned short*)(ws + B_WBD);
    unsigned short* wb3f = (unsigned short*)(ws + B_WB3);
    float* partA = (float*)(ws + B_H1H);              // reuse h1h+h2h (dead after conv3g)
    float* partB = (float*)(ws + B_PARTB);

    k_zero_ring<<<3120 + 128, 128, 0, stream>>>(h1h, h2h, xth, prod);
    k_prodx<<<dim3(128, 8, Bsz), dim3(32, 8), 0, stream>>>(x_ref, x_next, xth, prod);
    k_packall<<<4896, 256, 0, stream>>>(w2, wd, w3, wb2f, wbdf, wb3f);
    k_conv1c<<<NPIX / 32, 256, 0, stream>>>(prod, w1, b1, h1h);
    k_conv2g<<<512, 256, 0, stream>>>(h1h, wb2f, b2, h2h);
    k_conv3g<<<256, 256, 0, stream>>>(h2h, wb3f, b3, offp);
    k_dcng<<<512, 512, 0, stream>>>(xth, offp, wbdf, partA, partB);
    k_comb<<<4096, 256, 0, stream>>>(partA, partB, x_next, out);
}

// Round 16
// 93.590 us; speedup vs baseline: 1.1688x; 1.1688x over previous
//
#include <hip/hip_runtime.h>

typedef __attribute__((ext_vector_type(8))) short short8v;
typedef __attribute__((ext_vector_type(4))) float f32x4;
typedef __attribute__((ext_vector_type(2))) float f32x2;
typedef __attribute__((ext_vector_type(4))) unsigned int u32x4;

constexpr int Bsz = 4;
constexpr int Hh = 64, Wwd = 64;
constexpr int HWp = Hh * Wwd;            // 4096
constexpr int NPIX = Bsz * HWp;          // 16384
constexpr int HH = 66;                   // halo dim
constexpr int HPIX = HH * HH;            // 4356
constexpr int Kdim = 2304;               // 9*256
constexpr int NSTEP = 36;                // Kdim / 64

// ---- workspace byte offsets
constexpr size_t B_H1H  = 0;
constexpr size_t HALO_BYTES = (size_t)Bsz * HPIX * 256 * 2;      // 8,921,088
constexpr size_t B_H2H  = B_H1H + HALO_BYTES;
constexpr size_t B_XTH  = B_H2H + HALO_BYTES;
constexpr size_t B_PROD = B_XTH + HALO_BYTES;
constexpr size_t B_OFFP = B_PROD + (size_t)NPIX * 4;
constexpr size_t B_WB2  = B_OFFP + (size_t)NPIX * 32 * 4;        // frag-packed (32-o tiles)
constexpr size_t B_WBD  = B_WB2 + (size_t)256 * Kdim * 2;        // frag-packed (32-o tiles)
constexpr size_t B_WB3  = B_WBD + (size_t)256 * Kdim * 2;        // frag-packed (one 32-o tile)

static __device__ __forceinline__ unsigned short f2bf(float f) {
    unsigned u = __builtin_bit_cast(unsigned, f);
    u += 0x7FFFu + ((u >> 16) & 1u);
    return (unsigned short)(u >> 16);
}
static __device__ __forceinline__ unsigned cvt_pk_bf16(float lo, float hi) {
    unsigned r;
    asm("v_cvt_pk_bf16_f32 %0, %1, %2" : "=v"(r) : "v"(lo), "v"(hi));
    return r;
}
static __device__ __forceinline__ f32x2 pk_mul(f32x2 a, f32x2 b) {
    f32x2 d;
    asm("v_pk_mul_f32 %0, %1, %2" : "=v"(d) : "v"(a), "v"(b));
    return d;
}
static __device__ __forceinline__ f32x2 pk_fma(f32x2 a, f32x2 b, f32x2 c) {
    f32x2 d;
    asm("v_pk_fma_f32 %0, %1, %2, %3" : "=v"(d) : "v"(a), "v"(b), "v"(c));
    return d;
}
static __device__ __forceinline__ f32x2 unpack2(unsigned u) {
    f32x2 v;
    v.x = __builtin_bit_cast(float, u << 16);
    v.y = __builtin_bit_cast(float, u & 0xFFFF0000u);
    return v;
}
static __device__ __forceinline__ int swz(int u) {
    return (((u & 7) ^ ((u >> 3) & 7)) << 3);
}

// ---------------------------------------------------------------- merged init: weight packs + halo-ring/prod zero
// [0,2304): wb2f; [2304,4608): wbdf; [4608,4896): wb3f; [4896,6520): zero (2 sub-blocks of 128 thr each)
__global__ void k_init(const float* __restrict__ w2, const float* __restrict__ wd,
                       const float* __restrict__ w3,
                       unsigned short* __restrict__ wb2f, unsigned short* __restrict__ wbdf,
                       unsigned short* __restrict__ wb3f,
                       unsigned short* h1h, unsigned short* h2h, unsigned short* xth,
                       float* prod) {
    int blk = blockIdx.x;
    if (blk < 4608) {
        const float* w = (blk < 2304) ? w2 : wd;
        unsigned short* out = (blk < 2304) ? wb2f : wbdf;
        int i = (blk % 2304) * 256 + threadIdx.x;
        int e = i & 7;
        int lane = (i >> 3) & 63;
        int mi = (i >> 9) & 1;
        int kf = (i >> 10) & 1;
        int rest = i >> 11;                           // [0,288)
        int s = rest % 36;
        int wv = rest / 36;
        int o = wv * 32 + mi * 16 + (lane & 15);
        int kk = s * 64 + (kf * 4 + (lane >> 4)) * 8 + e;
        int c = kk & 255, tap = kk >> 8;
        out[i] = f2bf(w[((size_t)o * 256 + c) * 9 + tap]);
    } else if (blk < 4896) {
        int i = (blk - 4608) * 256 + threadIdx.x;
        int e = i & 7;
        int lane = (i >> 3) & 63;
        int oi = (i >> 9) & 1;
        int kf = (i >> 10) & 1;
        int s = i >> 11;                              // [0,36)
        int o = oi * 16 + (lane & 15);
        int kk = s * 64 + (kf * 4 + (lane >> 4)) * 8 + e;
        int c = kk & 255, tap = kk >> 8;
        float v = (o < 18) ? w3[((size_t)o * 256 + c) * 9 + tap] : 0.f;
        wb3f[i] = f2bf(v);
    } else {
        int sub = (blk - 4896) * 2 + (threadIdx.x >> 7);   // [0,3248)
        int t = threadIdx.x & 127;
        if (sub >= 3120) {                                  // prod zero: 128 sub x 128 thr x 4B
            unsigned* p = (unsigned*)prod + (size_t)(sub - 3120) * 128 + t;
            *p = 0;
            return;
        }
        int img = sub / 260;
        int rp = sub - img * 260;
        int buf = img >> 2, b = img & 3;
        int y, x;
        if (rp < 66) { y = 0; x = rp; }
        else if (rp < 132) { y = 65; x = rp - 66; }
        else { int s2 = rp - 132; y = 1 + (s2 >> 1); x = (s2 & 1) * 65; }
        unsigned short* base = (buf == 0) ? h1h : (buf == 1) ? h2h : xth;
        unsigned* p = (unsigned*)(base + ((size_t)b * HPIX + y * HH + x) * 256);
        p[t] = 0;
    }
}

// ---------------------------------------------------------------- fused: x_ref->xth transpose + prod partial
__global__ void k_prodx(const float* __restrict__ xr, const float* __restrict__ xn,
                        unsigned short* __restrict__ xth, float* __restrict__ prod) {
    __shared__ float t[32][33];
    __shared__ float red[8][33];
    int b = blockIdx.z;
    int c0 = blockIdx.y * 32;
    int y = blockIdx.x >> 1, x0 = (blockIdx.x & 1) * 32;
    int tx = threadIdx.x, ty = threadIdx.y;
    float part = 0.f;
#pragma unroll
    for (int i = 0; i < 32; i += 8) {
        size_t idx = ((size_t)b * 256 + c0 + ty + i) * HWp + y * Wwd + x0 + tx;
        float vr = xr[idx];
        float vn = xn[idx];
        t[ty + i][tx] = vr;
        part = fmaf(vr, vn, part);
    }
    red[ty][tx] = part;
    __syncthreads();
#pragma unroll
    for (int i = 0; i < 32; i += 8)
        xth[((size_t)b * HPIX + (y + 1) * HH + (x0 + ty + i + 1)) * 256 + c0 + tx] =
            f2bf(t[tx][ty + i]);
    if (ty == 0) {
        float s = red[0][tx] + red[1][tx] + red[2][tx] + red[3][tx] +
                  red[4][tx] + red[5][tx] + red[6][tx] + red[7][tx];
        atomicAdd(&prod[b * HWp + y * Wwd + x0 + tx], s);
    }
}

// ---------------------------------------------------------------- fused: corr (box3x3+leaky) + conv1 -> h1h
__global__ __launch_bounds__(256) void k_conv1c(const float* __restrict__ prod,
                                                const float* __restrict__ w1,
                                                const float* __restrict__ b1,
                                                unsigned short* __restrict__ h1h) {
    __shared__ float pp[5][36];
    __shared__ float pt[3][34];
    int px0 = blockIdx.x * 32;
    int b = px0 >> 12, y = (px0 & 4095) >> 6, x0 = px0 & 63;
    int tid = threadIdx.x;
    if (tid < 180) {
        int i = tid / 36, j = tid - i * 36;
        int yy = y - 2 + i, xx = x0 - 2 + j;
        float v = 0.f;
        if (yy >= 0 && yy < Hh && xx >= 0 && xx < Wwd) v = prod[b * HWp + yy * Wwd + xx];
        pp[i][j] = v;
    }
    __syncthreads();
    if (tid < 102) {
        int i = tid / 34, j = tid - i * 34;
        int yy = y - 1 + i, xx = x0 - 1 + j;
        float v = 0.f;
        if (yy >= 0 && yy < Hh && xx >= 0 && xx < Wwd) {
            float s = pp[i][j]     + pp[i][j + 1]     + pp[i][j + 2] +
                      pp[i + 1][j] + pp[i + 1][j + 1] + pp[i + 1][j + 2] +
                      pp[i + 2][j] + pp[i + 2][j + 1] + pp[i + 2][j + 2];
            s *= (1.0f / 256.0f);
            v = (s > 0.f) ? s : 0.1f * s;
        }
        pt[i][j] = v;
    }
    float wl[9];
#pragma unroll
    for (int k = 0; k < 9; ++k) wl[k] = w1[tid * 9 + k];
    float bias = b1[tid];
    __syncthreads();
    for (int p = 0; p < 32; ++p) {
        float acc = bias;
#pragma unroll
        for (int ky = 0; ky < 3; ++ky)
#pragma unroll
            for (int kx = 0; kx < 3; ++kx) acc = fmaf(pt[ky][p + kx], wl[ky * 3 + kx], acc);
        acc = fmaxf(acc, 0.f);
        h1h[((size_t)b * HPIX + (y + 1) * HH + (x0 + p + 1)) * 256 + tid] = f2bf(acc);
    }
}

// ---------------------------------------------------------------- conv2 GEMM: 64px x 128o, 4 waves, 2 blocks/CU, ITER2
__global__ __launch_bounds__(256) void k_conv2g(const unsigned short* __restrict__ h1h,
                                                const unsigned short* __restrict__ wbf,
                                                const float* __restrict__ bias,
                                                unsigned short* __restrict__ h2h) {
    __shared__ short S_s[4][64 * 64];                 // 4 bufs, 32 KB
    const int tid = threadIdx.x;
    const int bid = blockIdx.x;
    const int lin = (bid & 7) * 64 + (bid >> 3);      // XCD-bijective, 512 blocks
    const int px0 = (lin >> 1) * 64;
    const int oblk = lin & 1;
    const int b = px0 >> 12;
    const unsigned short* hb = h1h + (size_t)b * HPIX * 256;
    const int pxl = tid >> 2;
    const int px = px0 + pxl;
    const int y = (px & 4095) >> 6, x = px & 63;
    const int u0 = (tid & 3) * 2;
    const int lane = tid & 63, wv = tid >> 6;
    const int ot = oblk * 4 + wv;                      // global 32-o tile
    const unsigned short* wfb = wbf + (size_t)ot * NSTEP * 2048 + lane * 8;
    const unsigned short* abase0 = hb + (size_t)((y + 1) * HH + (x + 1)) * 256 + u0 * 8;

    f32x4 acc[4][2] = {};
    u32x4 wA[2][4], wB[2][4];
    u32x4 aP[4], aQ[4];
    float bia[2];
#pragma unroll
    for (int oi = 0; oi < 2; ++oi) bia[oi] = bias[ot * 32 + oi * 16 + (lane & 15)];

    const int wr0 = pxl * 64 + ((u0 ^ (pxl & 7)) << 3);
    const int wr1 = pxl * 64 + (((u0 + 1) ^ (pxl & 7)) << 3);

    auto WLOAD = [&](int s, u32x4 (&wreg)[4]) {
#pragma unroll
        for (int f = 0; f < 4; ++f)
            wreg[f] = *(const u32x4*)(wfb + ((size_t)s * 4 + f) * 512);
    };
    auto ALOAD = [&](int s, u32x4& a0, u32x4& a1) {
        int tap = s >> 2, chunk = s & 3;
        int aoff = ((tap / 3 - 1) * HH + (tap % 3 - 1)) * 256 + chunk * 64;
        a0 = *(const u32x4*)(abase0 + aoff);
        a1 = *(const u32x4*)(abase0 + aoff + 8);
    };

    {
        u32x4 a0, a1, a2, a3;
        ALOAD(0, a0, a1);
        ALOAD(1, a2, a3);
        WLOAD(0, wA[0]);
        WLOAD(1, wA[1]);
        *(u32x4*)&S_s[0][wr0] = a0;
        *(u32x4*)&S_s[0][wr1] = a1;
        *(u32x4*)&S_s[1][wr0] = a2;
        *(u32x4*)&S_s[1][wr1] = a3;
        ALOAD(2, aP[0], aP[1]);
        ALOAD(3, aP[2], aP[3]);
        asm volatile("s_waitcnt lgkmcnt(0)" ::: "memory");
    }

    auto ITER2 = [&](int s, u32x4 (&wcur)[2][4], u32x4 (&wnxt)[2][4],
                     u32x4 (&aC)[4], u32x4 (&aN)[4], short* SBc, short* SBn) {
        __builtin_amdgcn_s_barrier();
        __builtin_amdgcn_sched_barrier(0);
        if (s + 2 < NSTEP) {
            *(u32x4*)&SBn[wr0] = aC[0];
            *(u32x4*)&SBn[wr1] = aC[1];
            *(u32x4*)&SBn[64 * 64 + wr0] = aC[2];
            *(u32x4*)&SBn[64 * 64 + wr1] = aC[3];
        }
        if (s + 4 < NSTEP) {
            ALOAD(s + 4, aN[0], aN[1]);
            ALOAD(s + 5, aN[2], aN[3]);
        }
        if (s + 2 < NSTEP) {
            WLOAD(s + 2, wnxt[0]);
            WLOAD(s + 3, wnxt[1]);
        }
#pragma unroll
        for (int half = 0; half < 2; ++half) {
            const short* SB = SBc + half * 64 * 64;
            short8v af[4][2];
#pragma unroll
            for (int pi = 0; pi < 4; ++pi) {
                int row = pi * 16 + (lane & 15);
#pragma unroll
                for (int kf = 0; kf < 2; ++kf) {
                    int c8 = kf * 4 + (lane >> 4);
                    af[pi][kf] = *(const short8v*)&SB[row * 64 + ((c8 ^ (row & 7)) << 3)];
                }
            }
            __builtin_amdgcn_s_setprio(1);
#pragma unroll
            for (int kf = 0; kf < 2; ++kf)
#pragma unroll
                for (int pi = 0; pi < 4; ++pi)
#pragma unroll
                    for (int oi = 0; oi < 2; ++oi)
                        acc[pi][oi] = __builtin_amdgcn_mfma_f32_16x16x32_bf16(
                            af[pi][kf], __builtin_bit_cast(short8v, wcur[half][kf * 2 + oi]),
                            acc[pi][oi], 0, 0, 0);
            __builtin_amdgcn_s_setprio(0);
        }
        asm volatile("s_waitcnt lgkmcnt(0)" ::: "memory");
    };

    for (int s4 = 0; s4 < NSTEP; s4 += 4) {
        ITER2(s4, wA, wB, aP, aQ, &S_s[0][0], &S_s[2][0]);
        ITER2(s4 + 2, wB, wA, aQ, aP, &S_s[2][0], &S_s[0][0]);
    }

#pragma unroll
    for (int pi = 0; pi < 4; ++pi) {
#pragma unroll
        for (int j = 0; j < 4; ++j) {
            int p2 = px0 + pi * 16 + (lane >> 4) * 4 + j;
            int yy = (p2 & 4095) >> 6, xx = p2 & 63;
            unsigned short* dst = h2h + ((size_t)b * HPIX + (yy + 1) * HH + (xx + 1)) * 256;
#pragma unroll
            for (int oi = 0; oi < 2; ++oi) {
                int o = ot * 32 + oi * 16 + (lane & 15);
                dst[o] = f2bf(fmaxf(acc[pi][oi][j] + bia[oi], 0.f));
            }
        }
    }
}

// ---------------------------------------------------------------- conv3 GEMM: 64px x 32o, 4 waves (16px each), ITER2
__global__ __launch_bounds__(256) void k_conv3g(const unsigned short* __restrict__ h2h,
                                                const unsigned short* __restrict__ wb3f,
                                                const float* __restrict__ bias,
                                                float* __restrict__ offp) {
    __shared__ short S_s[4][64 * 64];                 // 4 bufs, 32 KB
    const int tid = threadIdx.x;
    const int bid = blockIdx.x;
    const int px0 = ((bid & 7) * 32 + (bid >> 3)) * 64;   // XCD-bijective, 256 blocks
    const int b = px0 >> 12;
    const unsigned short* hb = h2h + (size_t)b * HPIX * 256;
    const int pxl = tid >> 2;
    const int px = px0 + pxl;
    const int y = (px & 4095) >> 6, x = px & 63;
    const int u0 = (tid & 3) * 2;
    const int lane = tid & 63, wv = tid >> 6;
    const unsigned short* wfb = wb3f + lane * 8;
    const unsigned short* abase0 = hb + (size_t)((y + 1) * HH + (x + 1)) * 256 + u0 * 8;

    f32x4 acc[2] = {};
    u32x4 wA[2][4], wB[2][4];
    u32x4 aP[4], aQ[4];
    float bia[2];
#pragma unroll
    for (int oi = 0; oi < 2; ++oi) {
        int o = oi * 16 + (lane & 15);
        bia[oi] = (o < 18) ? bias[o] : 0.f;
    }

    const int wr0 = pxl * 64 + ((u0 ^ (pxl & 7)) << 3);
    const int wr1 = pxl * 64 + (((u0 + 1) ^ (pxl & 7)) << 3);

    auto WLOAD = [&](int s, u32x4 (&wreg)[4]) {
#pragma unroll
        for (int f = 0; f < 4; ++f)
            wreg[f] = *(const u32x4*)(wfb + ((size_t)s * 4 + f) * 512);
    };
    auto ALOAD = [&](int s, u32x4& a0, u32x4& a1) {
        int tap = s >> 2, chunk = s & 3;
        int aoff = ((tap / 3 - 1) * HH + (tap % 3 - 1)) * 256 + chunk * 64;
        a0 = *(const u32x4*)(abase0 + aoff);
        a1 = *(const u32x4*)(abase0 + aoff + 8);
    };

    {
        u32x4 a0, a1, a2, a3;
        ALOAD(0, a0, a1);
        ALOAD(1, a2, a3);
        WLOAD(0, wA[0]);
        WLOAD(1, wA[1]);
        *(u32x4*)&S_s[0][wr0] = a0;
        *(u32x4*)&S_s[0][wr1] = a1;
        *(u32x4*)&S_s[1][wr0] = a2;
        *(u32x4*)&S_s[1][wr1] = a3;
        ALOAD(2, aP[0], aP[1]);
        ALOAD(3, aP[2], aP[3]);
        asm volatile("s_waitcnt lgkmcnt(0)" ::: "memory");
    }

    auto ITER2 = [&](int s, u32x4 (&wcur)[2][4], u32x4 (&wnxt)[2][4],
                     u32x4 (&aC)[4], u32x4 (&aN)[4], short* SBc, short* SBn) {
        __builtin_amdgcn_s_barrier();
        __builtin_amdgcn_sched_barrier(0);
        if (s + 2 < NSTEP) {
            *(u32x4*)&SBn[wr0] = aC[0];
            *(u32x4*)&SBn[wr1] = aC[1];
            *(u32x4*)&SBn[64 * 64 + wr0] = aC[2];
            *(u32x4*)&SBn[64 * 64 + wr1] = aC[3];
        }
        if (s + 4 < NSTEP) {
            ALOAD(s + 4, aN[0], aN[1]);
            ALOAD(s + 5, aN[2], aN[3]);
        }
        if (s + 2 < NSTEP) {
            WLOAD(s + 2, wnxt[0]);
            WLOAD(s + 3, wnxt[1]);
        }
#pragma unroll
        for (int half = 0; half < 2; ++half) {
            const short* SB = SBc + half * 64 * 64;
            short8v af[2];
#pragma unroll
            for (int kf = 0; kf < 2; ++kf) {
                int row = wv * 16 + (lane & 15);
                int c8 = kf * 4 + (lane >> 4);
                af[kf] = *(const short8v*)&SB[row * 64 + ((c8 ^ (row & 7)) << 3)];
            }
            __builtin_amdgcn_s_setprio(1);
#pragma unroll
            for (int kf = 0; kf < 2; ++kf)
#pragma unroll
                for (int oi = 0; oi < 2; ++oi)
                    acc[oi] = __builtin_amdgcn_mfma_f32_16x16x32_bf16(
                        af[kf], __builtin_bit_cast(short8v, wcur[half][kf * 2 + oi]),
                        acc[oi], 0, 0, 0);
            __builtin_amdgcn_s_setprio(0);
        }
        asm volatile("s_waitcnt lgkmcnt(0)" ::: "memory");
    };

    for (int s4 = 0; s4 < NSTEP; s4 += 4) {
        ITER2(s4, wA, wB, aP, aQ, &S_s[0][0], &S_s[2][0]);
        ITER2(s4 + 2, wB, wA, aQ, aP, &S_s[2][0], &S_s[0][0]);
    }

#pragma unroll
    for (int j = 0; j < 4; ++j) {
        int p2 = px0 + wv * 16 + (lane >> 4) * 4 + j;
#pragma unroll
        for (int oi = 0; oi < 2; ++oi) {
            int o = oi * 16 + (lane & 15);
            offp[(size_t)p2 * 32 + o] = fmaxf(acc[oi][j] + bia[oi], 0.f);
        }
    }
}

// ---------------------------------------------------------------- dcn GEMM: 64px x 256o, 8 waves, ITER2 (R14)
__global__ __launch_bounds__(512) void k_dcng(const unsigned short* __restrict__ xth,
                                              const float* __restrict__ offp,
                                              const unsigned short* __restrict__ wbf,
                                              const float* __restrict__ xn,
                                              float* __restrict__ out) {
    __shared__ short S_s[4][64 * 64];                 // 4 bufs, 32 KB
    const int tid = threadIdx.x;
    const int bid = blockIdx.x;
    const int px0 = ((bid & 7) * 32 + (bid >> 3)) * 64;   // XCD-bijective
    const int b = px0 >> 12;
    const unsigned short* xb = xth + (size_t)b * HPIX * 256;
    const int pxl = tid >> 3;
    const int px = px0 + pxl;
    const int y = (px & 4095) >> 6, x = px & 63;
    const int u0 = tid & 7;
    const int lane = tid & 63, wv = tid >> 6;
    const unsigned short* wfb = wbf + (size_t)wv * NSTEP * 2048 + lane * 8;
    const float2* offv = (const float2*)offp;

    f32x4 acc[2][4] = {};
    u32x4 wA[2][4], wB[2][4];
    u32x4 g[2][4];
    const int wr0 = pxl * 64 + ((u0 ^ (pxl & 7)) << 3);

    const unsigned short* pcorner[4];
    f32x2 wpair[4];
    float2 offn;

    auto SETUP = [&](int tap, float dyo, float dxo) {
        int ky = tap / 3 - 1, kx = tap % 3 - 1;
        float ypos = (float)(y + ky) + dyo;
        float xpos = (float)(x + kx) + dxo;
        float y0f = floorf(ypos), x0f = floorf(xpos);
        float wy = ypos - y0f, wx = xpos - x0f;
        int y0 = (int)y0f, x0 = (int)x0f;
        bool y0v = (y0 >= 0) && (y0 < Hh), y1v = (y0 + 1 >= 0) && (y0 + 1 < Hh);
        bool x0v = (x0 >= 0) && (x0 < Wwd), x1v = (x0 + 1 >= 0) && (x0 + 1 < Wwd);
        int hy0 = min(max(y0, -1), 64) + 1, hy1 = min(max(y0 + 1, -1), 64) + 1;
        int hx0 = min(max(x0, -1), 64) + 1, hx1 = min(max(x0 + 1, -1), 64) + 1;
        float w0 = (1.f - wy) * (1.f - wx) * (float)(y0v && x0v);
        float w1 = (1.f - wy) * wx * (float)(y0v && x1v);
        float w2 = wy * (1.f - wx) * (float)(y1v && x0v);
        float w3 = wy * wx * (float)(y1v && x1v);
        wpair[0] = (f32x2){w0, w0};
        wpair[1] = (f32x2){w1, w1};
        wpair[2] = (f32x2){w2, w2};
        wpair[3] = (f32x2){w3, w3};
        pcorner[0] = xb + (size_t)((hy0 * HH + hx0) * 256) + u0 * 8;
        pcorner[1] = xb + (size_t)((hy0 * HH + hx1) * 256) + u0 * 8;
        pcorner[2] = xb + (size_t)((hy1 * HH + hx0) * 256) + u0 * 8;
        pcorner[3] = xb + (size_t)((hy1 * HH + hx1) * 256) + u0 * 8;
    };
    auto WLOAD = [&](int s, u32x4 (&wreg)[4]) {
#pragma unroll
        for (int f = 0; f < 4; ++f)
            wreg[f] = *(const u32x4*)(wfb + ((size_t)s * 4 + f) * 512);
    };
    auto GISSUE = [&](int s, u32x4 (&gr)[4]) {
        const int nco = (s & 3) * 64;
#pragma unroll
        for (int c = 0; c < 4; ++c) gr[c] = *(const u32x4*)(pcorner[c] + nco);
    };
    auto COMBINE_WRITE = [&](u32x4 (&gr)[4], short* SBn) {
        u32x4 res;
#pragma unroll
        for (int qd = 0; qd < 4; ++qd) {
            f32x2 a = pk_mul(unpack2(gr[0][qd]), wpair[0]);
            a = pk_fma(unpack2(gr[1][qd]), wpair[1], a);
            a = pk_fma(unpack2(gr[2][qd]), wpair[2], a);
            a = pk_fma(unpack2(gr[3][qd]), wpair[3], a);
            res[qd] = cvt_pk_bf16(a.x, a.y);
        }
        *(u32x4*)&SBn[wr0] = res;
    };

    {
        float2 o0 = offv[(size_t)px * 16];
        SETUP(0, o0.x, o0.y);
        u32x4 g0[4], g1[4];
        GISSUE(0, g0);
        GISSUE(1, g1);
        WLOAD(0, wA[0]);
        WLOAD(1, wA[1]);
        COMBINE_WRITE(g0, &S_s[0][0]);
        COMBINE_WRITE(g1, &S_s[1][0]);
        GISSUE(2, g[0]);
        GISSUE(3, g[1]);
        offn = offv[(size_t)px * 16 + 1];
        asm volatile("s_waitcnt lgkmcnt(0)" ::: "memory");
    }

    auto ITER2 = [&](int s, u32x4 (&wcur)[2][4], u32x4 (&wnxt)[2][4], short* SBc, short* SBn) {
        __builtin_amdgcn_s_barrier();
        __builtin_amdgcn_sched_barrier(0);
        if (s + 2 < NSTEP) {
            COMBINE_WRITE(g[0], SBn);
            COMBINE_WRITE(g[1], SBn + 64 * 64);
        }
        if ((s & 3) == 0 && s + 4 < NSTEP)
            SETUP((s + 4) >> 2, offn.x, offn.y);
        if ((s & 3) == 2 && ((s + 8) >> 2) < 9)
            offn = offv[(size_t)px * 16 + ((s + 8) >> 2)];
        if (s + 4 < NSTEP) {
            GISSUE(s + 4, g[0]);
            GISSUE(s + 5, g[1]);
        }
        if (s + 2 < NSTEP) {
            WLOAD(s + 2, wnxt[0]);
            WLOAD(s + 3, wnxt[1]);
        }
#pragma unroll
        for (int half = 0; half < 2; ++half) {
            const short* SB = SBc + half * 64 * 64;
            short8v sf[4][2];
#pragma unroll
            for (int ni = 0; ni < 4; ++ni) {
                int row = ni * 16 + (lane & 15);
#pragma unroll
                for (int kf = 0; kf < 2; ++kf) {
                    int c8 = kf * 4 + (lane >> 4);
                    sf[ni][kf] = *(const short8v*)&SB[row * 64 + ((c8 ^ (row & 7)) << 3)];
                }
            }
            __builtin_amdgcn_s_setprio(1);
#pragma unroll
            for (int kf = 0; kf < 2; ++kf)
#pragma unroll
                for (int mi = 0; mi < 2; ++mi)
#pragma unroll
                    for (int ni = 0; ni < 4; ++ni)
                        acc[mi][ni] = __builtin_amdgcn_mfma_f32_16x16x32_bf16(
                            __builtin_bit_cast(short8v, wcur[half][kf * 2 + mi]), sf[ni][kf],
                            acc[mi][ni], 0, 0, 0);
            __builtin_amdgcn_s_setprio(0);
        }
        asm volatile("s_waitcnt lgkmcnt(0)" ::: "memory");
    };

    for (int s4 = 0; s4 < NSTEP; s4 += 4) {
        ITER2(s4, wA, wB, &S_s[0][0], &S_s[2][0]);
        ITER2(s4 + 2, wB, wA, &S_s[2][0], &S_s[0][0]);
    }

#pragma unroll
    for (int mi = 0; mi < 2; ++mi) {
        int o = wv * 32 + mi * 16 + (lane >> 4) * 4;
#pragma unroll
        for (int j = 0; j < 4; ++j) {
            size_t rowbase = ((size_t)b * 256 + o + j) * HWp;
#pragma unroll
            for (int ni = 0; ni < 4; ++ni) {
                int p2 = (px0 + ni * 16 + (lane & 15)) & 4095;
                size_t idx = rowbase + p2;
                out[idx] = 0.5f * (xn[idx] + fmaxf(acc[mi][ni][j], 0.f));
            }
        }
    }
}

extern "C" void kernel_launch(void* const* d_in, const int* in_sizes, int n_in,
                              void* d_out, int out_size, void* d_ws, size_t ws_size,
                              hipStream_t stream) {
    const float* x_ref  = (const float*)d_in[0];
    const float* x_next = (const float*)d_in[1];
    const float* w1 = (const float*)d_in[2];
    const float* b1 = (const float*)d_in[3];
    const float* w2 = (const float*)d_in[4];
    const float* b2 = (const float*)d_in[5];
    const float* w3 = (const float*)d_in[6];
    const float* b3 = (const float*)d_in[7];
    const float* wd = (const float*)d_in[8];
    float* out = (float*)d_out;
    char* ws = (char*)d_ws;

    unsigned short* h1h = (unsigned short*)(ws + B_H1H);
    unsigned short* h2h = (unsigned short*)(ws + B_H2H);
    unsigned short* xth = (unsigned short*)(ws + B_XTH);
    float* prod = (float*)(ws + B_PROD);
    float* offp = (float*)(ws + B_OFFP);
    unsigned short* wb2f = (unsigned short*)(ws + B_WB2);
    unsigned short* wbdf = (unsigned short*)(ws + B_WBD);
    unsigned short* wb3f = (unsigned short*)(ws + B_WB3);

    k_init<<<6520, 256, 0, stream>>>(w2, wd, w3, wb2f, wbdf, wb3f, h1h, h2h, xth, prod);
    k_prodx<<<dim3(128, 8, Bsz), dim3(32, 8), 0, stream>>>(x_ref, x_next, xth, prod);
    k_conv1c<<<NPIX / 32, 256, 0, stream>>>(prod, w1, b1, h1h);
    k_conv2g<<<512, 256, 0, stream>>>(h1h, wb2f, b2, h2h);
    k_conv3g<<<256, 256, 0, stream>>>(h2h, wb3f, b3, offp);
    k_dcng<<<256, 512, 0, stream>>>(xth, offp, wbdf, x_next, out);
}

// Round 17
// 91.456 us; speedup vs baseline: 1.1961x; 1.0233x over previous
//
#include <hip/hip_runtime.h>

typedef __attribute__((ext_vector_type(8))) short short8v;
typedef __attribute__((ext_vector_type(4))) float f32x4;
typedef __attribute__((ext_vector_type(2))) float f32x2;
typedef __attribute__((ext_vector_type(4))) unsigned int u32x4;

constexpr int Bsz = 4;
constexpr int Hh = 64, Wwd = 64;
constexpr int HWp = Hh * Wwd;            // 4096
constexpr int NPIX = Bsz * HWp;          // 16384
constexpr int HH = 66;                   // halo dim
constexpr int HPIX = HH * HH;            // 4356
constexpr int Kdim = 2304;               // 9*256
constexpr int NSTEP = 36;                // Kdim / 64

// ---- workspace byte offsets
constexpr size_t B_H1H  = 0;
constexpr size_t HALO_BYTES = (size_t)Bsz * HPIX * 256 * 2;      // 8,921,088
constexpr size_t B_H2H  = B_H1H + HALO_BYTES;
constexpr size_t B_XTH  = B_H2H + HALO_BYTES;
constexpr size_t B_PROD8 = B_XTH + HALO_BYTES;                   // 8 x NPIX fp32 slices
constexpr size_t B_OFFP = B_PROD8 + (size_t)NPIX * 8 * 4;
constexpr size_t B_WB2  = B_OFFP + (size_t)NPIX * 32 * 4;        // frag-packed (32-o tiles)
constexpr size_t B_WBD  = B_WB2 + (size_t)256 * Kdim * 2;        // frag-packed (32-o tiles)
constexpr size_t B_WB3  = B_WBD + (size_t)256 * Kdim * 2;        // frag-packed (one 32-o tile)

static __device__ __forceinline__ unsigned short f2bf(float f) {
    unsigned u = __builtin_bit_cast(unsigned, f);
    u += 0x7FFFu + ((u >> 16) & 1u);
    return (unsigned short)(u >> 16);
}
static __device__ __forceinline__ unsigned cvt_pk_bf16(float lo, float hi) {
    unsigned r;
    asm("v_cvt_pk_bf16_f32 %0, %1, %2" : "=v"(r) : "v"(lo), "v"(hi));
    return r;
}
static __device__ __forceinline__ f32x2 pk_mul(f32x2 a, f32x2 b) {
    f32x2 d;
    asm("v_pk_mul_f32 %0, %1, %2" : "=v"(d) : "v"(a), "v"(b));
    return d;
}
static __device__ __forceinline__ f32x2 pk_fma(f32x2 a, f32x2 b, f32x2 c) {
    f32x2 d;
    asm("v_pk_fma_f32 %0, %1, %2, %3" : "=v"(d) : "v"(a), "v"(b), "v"(c));
    return d;
}
static __device__ __forceinline__ f32x2 unpack2(unsigned u) {
    f32x2 v;
    v.x = __builtin_bit_cast(float, u << 16);
    v.y = __builtin_bit_cast(float, u & 0xFFFF0000u);
    return v;
}
static __device__ __forceinline__ int swz(int u) {
    return (((u & 7) ^ ((u >> 3) & 7)) << 3);
}

// ---------------------------------------------------------------- merged init: packs + ring zeros + prodx
// [0,2304): wb2f; [2304,4608): wbdf; [4608,4896): wb3f; [4896,6456): ring zeros; [6456,10552): prodx
__global__ void k_initx(const float* __restrict__ w2, const float* __restrict__ wd,
                        const float* __restrict__ w3,
                        unsigned short* __restrict__ wb2f, unsigned short* __restrict__ wbdf,
                        unsigned short* __restrict__ wb3f,
                        unsigned short* h1h, unsigned short* h2h, unsigned short* xth,
                        const float* __restrict__ xr, const float* __restrict__ xn,
                        float* __restrict__ prod8) {
    __shared__ float t[32][33];
    __shared__ float red[8][33];
    int blk = blockIdx.x;
    if (blk < 4608) {
        const float* w = (blk < 2304) ? w2 : wd;
        unsigned short* out = (blk < 2304) ? wb2f : wbdf;
        int i = (blk % 2304) * 256 + threadIdx.x;
        int e = i & 7;
        int lane = (i >> 3) & 63;
        int mi = (i >> 9) & 1;
        int kf = (i >> 10) & 1;
        int rest = i >> 11;                           // [0,288)
        int s = rest % 36;
        int wv = rest / 36;
        int o = wv * 32 + mi * 16 + (lane & 15);
        int kk = s * 64 + (kf * 4 + (lane >> 4)) * 8 + e;
        int c = kk & 255, tap = kk >> 8;
        out[i] = f2bf(w[((size_t)o * 256 + c) * 9 + tap]);
    } else if (blk < 4896) {
        int i = (blk - 4608) * 256 + threadIdx.x;
        int e = i & 7;
        int lane = (i >> 3) & 63;
        int oi = (i >> 9) & 1;
        int kf = (i >> 10) & 1;
        int s = i >> 11;                              // [0,36)
        int o = oi * 16 + (lane & 15);
        int kk = s * 64 + (kf * 4 + (lane >> 4)) * 8 + e;
        int c = kk & 255, tap = kk >> 8;
        float v = (o < 18) ? w3[((size_t)o * 256 + c) * 9 + tap] : 0.f;
        wb3f[i] = f2bf(v);
    } else if (blk < 6456) {
        int sub = (blk - 4896) * 2 + (threadIdx.x >> 7);   // [0,3120)
        int tt = threadIdx.x & 127;
        if (sub < 3120) {
            int img = sub / 260;
            int rp = sub - img * 260;
            int buf = img >> 2, b = img & 3;
            int y, x;
            if (rp < 66) { y = 0; x = rp; }
            else if (rp < 132) { y = 65; x = rp - 66; }
            else { int s2 = rp - 132; y = 1 + (s2 >> 1); x = (s2 & 1) * 65; }
            unsigned short* base = (buf == 0) ? h1h : (buf == 1) ? h2h : xth;
            unsigned* p = (unsigned*)(base + ((size_t)b * HPIX + y * HH + x) * 256);
            p[tt] = 0;
        }
    } else {
        // prodx: pb = ((b*8 + cg)*128 + bx)
        int pb = blk - 6456;
        int bx = pb & 127;
        int cg = (pb >> 7) & 7;
        int b = pb >> 10;
        int c0 = cg * 32;
        int y = bx >> 1, x0 = (bx & 1) * 32;
        int tx = threadIdx.x & 31, ty = threadIdx.x >> 5;
        float part = 0.f;
#pragma unroll
        for (int i = 0; i < 32; i += 8) {
            size_t idx = ((size_t)b * 256 + c0 + ty + i) * HWp + y * Wwd + x0 + tx;
            float vr = xr[idx];
            float vn = xn[idx];
            t[ty + i][tx] = vr;
            part = fmaf(vr, vn, part);
        }
        red[ty][tx] = part;
        __syncthreads();
#pragma unroll
        for (int i = 0; i < 32; i += 8)
            xth[((size_t)b * HPIX + (y + 1) * HH + (x0 + ty + i + 1)) * 256 + c0 + tx] =
                f2bf(t[tx][ty + i]);
        if (ty == 0) {
            float s = red[0][tx] + red[1][tx] + red[2][tx] + red[3][tx] +
                      red[4][tx] + red[5][tx] + red[6][tx] + red[7][tx];
            prod8[(size_t)cg * NPIX + b * HWp + y * Wwd + x0 + tx] = s;
        }
    }
}

// ---------------------------------------------------------------- fused: corr (box3x3+leaky) + conv1 -> h1h
__global__ __launch_bounds__(256) void k_conv1c(const float* __restrict__ prod8,
                                                const float* __restrict__ w1,
                                                const float* __restrict__ b1,
                                                unsigned short* __restrict__ h1h) {
    __shared__ float pp[5][36];
    __shared__ float pt[3][34];
    int px0 = blockIdx.x * 32;
    int b = px0 >> 12, y = (px0 & 4095) >> 6, x0 = px0 & 63;
    int tid = threadIdx.x;
    if (tid < 180) {
        int i = tid / 36, j = tid - i * 36;
        int yy = y - 2 + i, xx = x0 - 2 + j;
        float v = 0.f;
        if (yy >= 0 && yy < Hh && xx >= 0 && xx < Wwd) {
            size_t base = (size_t)b * HWp + yy * Wwd + xx;
#pragma unroll
            for (int cg = 0; cg < 8; ++cg) v += prod8[(size_t)cg * NPIX + base];
        }
        pp[i][j] = v;
    }
    __syncthreads();
    if (tid < 102) {
        int i = tid / 34, j = tid - i * 34;
        int yy = y - 1 + i, xx = x0 - 1 + j;
        float v = 0.f;
        if (yy >= 0 && yy < Hh && xx >= 0 && xx < Wwd) {
            float s = pp[i][j]     + pp[i][j + 1]     + pp[i][j + 2] +
                      pp[i + 1][j] + pp[i + 1][j + 1] + pp[i + 1][j + 2] +
                      pp[i + 2][j] + pp[i + 2][j + 1] + pp[i + 2][j + 2];
            s *= (1.0f / 256.0f);
            v = (s > 0.f) ? s : 0.1f * s;
        }
        pt[i][j] = v;
    }
    float wl[9];
#pragma unroll
    for (int k = 0; k < 9; ++k) wl[k] = w1[tid * 9 + k];
    float bias = b1[tid];
    __syncthreads();
    for (int p = 0; p < 32; ++p) {
        float acc = bias;
#pragma unroll
        for (int ky = 0; ky < 3; ++ky)
#pragma unroll
            for (int kx = 0; kx < 3; ++kx) acc = fmaf(pt[ky][p + kx], wl[ky * 3 + kx], acc);
        acc = fmaxf(acc, 0.f);
        h1h[((size_t)b * HPIX + (y + 1) * HH + (x0 + p + 1)) * 256 + tid] = f2bf(acc);
    }
}

// ---------------------------------------------------------------- conv2 GEMM: 64px x 128o, 4 waves, 2 blocks/CU, ITER2
__global__ __launch_bounds__(256) void k_conv2g(const unsigned short* __restrict__ h1h,
                                                const unsigned short* __restrict__ wbf,
                                                const float* __restrict__ bias,
                                                unsigned short* __restrict__ h2h) {
    __shared__ short S_s[4][64 * 64];                 // 4 bufs, 32 KB
    const int tid = threadIdx.x;
    const int bid = blockIdx.x;
    const int lin = (bid & 7) * 64 + (bid >> 3);      // XCD-bijective, 512 blocks
    const int px0 = (lin >> 1) * 64;
    const int oblk = lin & 1;
    const int b = px0 >> 12;
    const unsigned short* hb = h1h + (size_t)b * HPIX * 256;
    const int pxl = tid >> 2;
    const int px = px0 + pxl;
    const int y = (px & 4095) >> 6, x = px & 63;
    const int u0 = (tid & 3) * 2;
    const int lane = tid & 63, wv = tid >> 6;
    const int ot = oblk * 4 + wv;                      // global 32-o tile
    const unsigned short* wfb = wbf + (size_t)ot * NSTEP * 2048 + lane * 8;
    const unsigned short* abase0 = hb + (size_t)((y + 1) * HH + (x + 1)) * 256 + u0 * 8;

    f32x4 acc[4][2] = {};
    u32x4 wA[2][4], wB[2][4];
    u32x4 aP[4], aQ[4];
    float bia[2];
#pragma unroll
    for (int oi = 0; oi < 2; ++oi) bia[oi] = bias[ot * 32 + oi * 16 + (lane & 15)];

    const int wr0 = pxl * 64 + ((u0 ^ (pxl & 7)) << 3);
    const int wr1 = pxl * 64 + (((u0 + 1) ^ (pxl & 7)) << 3);

    auto WLOAD = [&](int s, u32x4 (&wreg)[4]) {
#pragma unroll
        for (int f = 0; f < 4; ++f)
            wreg[f] = *(const u32x4*)(wfb + ((size_t)s * 4 + f) * 512);
    };
    auto ALOAD = [&](int s, u32x4& a0, u32x4& a1) {
        int tap = s >> 2, chunk = s & 3;
        int aoff = ((tap / 3 - 1) * HH + (tap % 3 - 1)) * 256 + chunk * 64;
        a0 = *(const u32x4*)(abase0 + aoff);
        a1 = *(const u32x4*)(abase0 + aoff + 8);
    };

    {
        u32x4 a0, a1, a2, a3;
        ALOAD(0, a0, a1);
        ALOAD(1, a2, a3);
        WLOAD(0, wA[0]);
        WLOAD(1, wA[1]);
        *(u32x4*)&S_s[0][wr0] = a0;
        *(u32x4*)&S_s[0][wr1] = a1;
        *(u32x4*)&S_s[1][wr0] = a2;
        *(u32x4*)&S_s[1][wr1] = a3;
        ALOAD(2, aP[0], aP[1]);
        ALOAD(3, aP[2], aP[3]);
        asm volatile("s_waitcnt lgkmcnt(0)" ::: "memory");
    }

    auto ITER2 = [&](int s, u32x4 (&wcur)[2][4], u32x4 (&wnxt)[2][4],
                     u32x4 (&aC)[4], u32x4 (&aN)[4], short* SBc, short* SBn) {
        __builtin_amdgcn_s_barrier();
        __builtin_amdgcn_sched_barrier(0);
        if (s + 2 < NSTEP) {
            *(u32x4*)&SBn[wr0] = aC[0];
            *(u32x4*)&SBn[wr1] = aC[1];
            *(u32x4*)&SBn[64 * 64 + wr0] = aC[2];
            *(u32x4*)&SBn[64 * 64 + wr1] = aC[3];
        }
        if (s + 4 < NSTEP) {
            ALOAD(s + 4, aN[0], aN[1]);
            ALOAD(s + 5, aN[2], aN[3]);
        }
        if (s + 2 < NSTEP) {
            WLOAD(s + 2, wnxt[0]);
            WLOAD(s + 3, wnxt[1]);
        }
#pragma unroll
        for (int half = 0; half < 2; ++half) {
            const short* SB = SBc + half * 64 * 64;
            short8v af[4][2];
#pragma unroll
            for (int pi = 0; pi < 4; ++pi) {
                int row = pi * 16 + (lane & 15);
#pragma unroll
                for (int kf = 0; kf < 2; ++kf) {
                    int c8 = kf * 4 + (lane >> 4);
                    af[pi][kf] = *(const short8v*)&SB[row * 64 + ((c8 ^ (row & 7)) << 3)];
                }
            }
            __builtin_amdgcn_s_setprio(1);
#pragma unroll
            for (int kf = 0; kf < 2; ++kf)
#pragma unroll
                for (int pi = 0; pi < 4; ++pi)
#pragma unroll
                    for (int oi = 0; oi < 2; ++oi)
                        acc[pi][oi] = __builtin_amdgcn_mfma_f32_16x16x32_bf16(
                            af[pi][kf], __builtin_bit_cast(short8v, wcur[half][kf * 2 + oi]),
                            acc[pi][oi], 0, 0, 0);
            __builtin_amdgcn_s_setprio(0);
        }
        asm volatile("s_waitcnt lgkmcnt(0)" ::: "memory");
    };

    for (int s4 = 0; s4 < NSTEP; s4 += 4) {
        ITER2(s4, wA, wB, aP, aQ, &S_s[0][0], &S_s[2][0]);
        ITER2(s4 + 2, wB, wA, aQ, aP, &S_s[2][0], &S_s[0][0]);
    }

#pragma unroll
    for (int pi = 0; pi < 4; ++pi) {
#pragma unroll
        for (int j = 0; j < 4; ++j) {
            int p2 = px0 + pi * 16 + (lane >> 4) * 4 + j;
            int yy = (p2 & 4095) >> 6, xx = p2 & 63;
            unsigned short* dst = h2h + ((size_t)b * HPIX + (yy + 1) * HH + (xx + 1)) * 256;
#pragma unroll
            for (int oi = 0; oi < 2; ++oi) {
                int o = ot * 32 + oi * 16 + (lane & 15);
                dst[o] = f2bf(fmaxf(acc[pi][oi][j] + bia[oi], 0.f));
            }
        }
    }
}

// ---------------------------------------------------------------- conv3 GEMM: 64px x 32o, 4 waves (16px each), ITER2
__global__ __launch_bounds__(256) void k_conv3g(const unsigned short* __restrict__ h2h,
                                                const unsigned short* __restrict__ wb3f,
                                                const float* __restrict__ bias,
                                                float* __restrict__ offp) {
    __shared__ short S_s[4][64 * 64];                 // 4 bufs, 32 KB
    const int tid = threadIdx.x;
    const int bid = blockIdx.x;
    const int px0 = ((bid & 7) * 32 + (bid >> 3)) * 64;   // XCD-bijective, 256 blocks
    const int b = px0 >> 12;
    const unsigned short* hb = h2h + (size_t)b * HPIX * 256;
    const int pxl = tid >> 2;
    const int px = px0 + pxl;
    const int y = (px & 4095) >> 6, x = px & 63;
    const int u0 = (tid & 3) * 2;
    const int lane = tid & 63, wv = tid >> 6;
    const unsigned short* wfb = wb3f + lane * 8;
    const unsigned short* abase0 = hb + (size_t)((y + 1) * HH + (x + 1)) * 256 + u0 * 8;

    f32x4 acc[2] = {};
    u32x4 wA[2][4], wB[2][4];
    u32x4 aP[4], aQ[4];
    float bia[2];
#pragma unroll
    for (int oi = 0; oi < 2; ++oi) {
        int o = oi * 16 + (lane & 15);
        bia[oi] = (o < 18) ? bias[o] : 0.f;
    }

    const int wr0 = pxl * 64 + ((u0 ^ (pxl & 7)) << 3);
    const int wr1 = pxl * 64 + (((u0 + 1) ^ (pxl & 7)) << 3);

    auto WLOAD = [&](int s, u32x4 (&wreg)[4]) {
#pragma unroll
        for (int f = 0; f < 4; ++f)
            wreg[f] = *(const u32x4*)(wfb + ((size_t)s * 4 + f) * 512);
    };
    auto ALOAD = [&](int s, u32x4& a0, u32x4& a1) {
        int tap = s >> 2, chunk = s & 3;
        int aoff = ((tap / 3 - 1) * HH + (tap % 3 - 1)) * 256 + chunk * 64;
        a0 = *(const u32x4*)(abase0 + aoff);
        a1 = *(const u32x4*)(abase0 + aoff + 8);
    };

    {
        u32x4 a0, a1, a2, a3;
        ALOAD(0, a0, a1);
        ALOAD(1, a2, a3);
        WLOAD(0, wA[0]);
        WLOAD(1, wA[1]);
        *(u32x4*)&S_s[0][wr0] = a0;
        *(u32x4*)&S_s[0][wr1] = a1;
        *(u32x4*)&S_s[1][wr0] = a2;
        *(u32x4*)&S_s[1][wr1] = a3;
        ALOAD(2, aP[0], aP[1]);
        ALOAD(3, aP[2], aP[3]);
        asm volatile("s_waitcnt lgkmcnt(0)" ::: "memory");
    }

    auto ITER2 = [&](int s, u32x4 (&wcur)[2][4], u32x4 (&wnxt)[2][4],
                     u32x4 (&aC)[4], u32x4 (&aN)[4], short* SBc, short* SBn) {
        __builtin_amdgcn_s_barrier();
        __builtin_amdgcn_sched_barrier(0);
        if (s + 2 < NSTEP) {
            *(u32x4*)&SBn[wr0] = aC[0];
            *(u32x4*)&SBn[wr1] = aC[1];
            *(u32x4*)&SBn[64 * 64 + wr0] = aC[2];
            *(u32x4*)&SBn[64 * 64 + wr1] = aC[3];
        }
        if (s + 4 < NSTEP) {
            ALOAD(s + 4, aN[0], aN[1]);
            ALOAD(s + 5, aN[2], aN[3]);
        }
        if (s + 2 < NSTEP) {
            WLOAD(s + 2, wnxt[0]);
            WLOAD(s + 3, wnxt[1]);
        }
#pragma unroll
        for (int half = 0; half < 2; ++half) {
            const short* SB = SBc + half * 64 * 64;
            short8v af[2];
#pragma unroll
            for (int kf = 0; kf < 2; ++kf) {
                int row = wv * 16 + (lane & 15);
                int c8 = kf * 4 + (lane >> 4);
                af[kf] = *(const short8v*)&SB[row * 64 + ((c8 ^ (row & 7)) << 3)];
            }
            __builtin_amdgcn_s_setprio(1);
#pragma unroll
            for (int kf = 0; kf < 2; ++kf)
#pragma unroll
                for (int oi = 0; oi < 2; ++oi)
                    acc[oi] = __builtin_amdgcn_mfma_f32_16x16x32_bf16(
                        af[kf], __builtin_bit_cast(short8v, wcur[half][kf * 2 + oi]),
                        acc[oi], 0, 0, 0);
            __builtin_amdgcn_s_setprio(0);
        }
        asm volatile("s_waitcnt lgkmcnt(0)" ::: "memory");
    };

    for (int s4 = 0; s4 < NSTEP; s4 += 4) {
        ITER2(s4, wA, wB, aP, aQ, &S_s[0][0], &S_s[2][0]);
        ITER2(s4 + 2, wB, wA, aQ, aP, &S_s[2][0], &S_s[0][0]);
    }

#pragma unroll
    for (int j = 0; j < 4; ++j) {
        int p2 = px0 + wv * 16 + (lane >> 4) * 4 + j;
#pragma unroll
        for (int oi = 0; oi < 2; ++oi) {
            int o = oi * 16 + (lane & 15);
            offp[(size_t)p2 * 32 + o] = fmaxf(acc[oi][j] + bia[oi], 0.f);
        }
    }
}

// ---------------------------------------------------------------- dcn GEMM: 64px x 256o, 8 waves, ITER2 (R14)
__global__ __launch_bounds__(512) void k_dcng(const unsigned short* __restrict__ xth,
                                              const float* __restrict__ offp,
                                              const unsigned short* __restrict__ wbf,
                                              const float* __restrict__ xn,
                                              float* __restrict__ out) {
    __shared__ short S_s[4][64 * 64];                 // 4 bufs, 32 KB
    const int tid = threadIdx.x;
    const int bid = blockIdx.x;
    const int px0 = ((bid & 7) * 32 + (bid >> 3)) * 64;   // XCD-bijective
    const int b = px0 >> 12;
    const unsigned short* xb = xth + (size_t)b * HPIX * 256;
    const int pxl = tid >> 3;
    const int px = px0 + pxl;
    const int y = (px & 4095) >> 6, x = px & 63;
    const int u0 = tid & 7;
    const int lane = tid & 63, wv = tid >> 6;
    const unsigned short* wfb = wbf + (size_t)wv * NSTEP * 2048 + lane * 8;
    const float2* offv = (const float2*)offp;

    f32x4 acc[2][4] = {};
    u32x4 wA[2][4], wB[2][4];
    u32x4 g[2][4];
    const int wr0 = pxl * 64 + ((u0 ^ (pxl & 7)) << 3);

    const unsigned short* pcorner[4];
    f32x2 wpair[4];
    float2 offn;

    auto SETUP = [&](int tap, float dyo, float dxo) {
        int ky = tap / 3 - 1, kx = tap % 3 - 1;
        float ypos = (float)(y + ky) + dyo;
        float xpos = (float)(x + kx) + dxo;
        float y0f = floorf(ypos), x0f = floorf(xpos);
        float wy = ypos - y0f, wx = xpos - x0f;
        int y0 = (int)y0f, x0 = (int)x0f;
        bool y0v = (y0 >= 0) && (y0 < Hh), y1v = (y0 + 1 >= 0) && (y0 + 1 < Hh);
        bool x0v = (x0 >= 0) && (x0 < Wwd), x1v = (x0 + 1 >= 0) && (x0 + 1 < Wwd);
        int hy0 = min(max(y0, -1), 64) + 1, hy1 = min(max(y0 + 1, -1), 64) + 1;
        int hx0 = min(max(x0, -1), 64) + 1, hx1 = min(max(x0 + 1, -1), 64) + 1;
        float w0 = (1.f - wy) * (1.f - wx) * (float)(y0v && x0v);
        float w1 = (1.f - wy) * wx * (float)(y0v && x1v);
        float w2 = wy * (1.f - wx) * (float)(y1v && x0v);
        float w3 = wy * wx * (float)(y1v && x1v);
        wpair[0] = (f32x2){w0, w0};
        wpair[1] = (f32x2){w1, w1};
        wpair[2] = (f32x2){w2, w2};
        wpair[3] = (f32x2){w3, w3};
        pcorner[0] = xb + (size_t)((hy0 * HH + hx0) * 256) + u0 * 8;
        pcorner[1] = xb + (size_t)((hy0 * HH + hx1) * 256) + u0 * 8;
        pcorner[2] = xb + (size_t)((hy1 * HH + hx0) * 256) + u0 * 8;
        pcorner[3] = xb + (size_t)((hy1 * HH + hx1) * 256) + u0 * 8;
    };
    auto WLOAD = [&](int s, u32x4 (&wreg)[4]) {
#pragma unroll
        for (int f = 0; f < 4; ++f)
            wreg[f] = *(const u32x4*)(wfb + ((size_t)s * 4 + f) * 512);
    };
    auto GISSUE = [&](int s, u32x4 (&gr)[4]) {
        const int nco = (s & 3) * 64;
#pragma unroll
        for (int c = 0; c < 4; ++c) gr[c] = *(const u32x4*)(pcorner[c] + nco);
    };
    auto COMBINE_WRITE = [&](u32x4 (&gr)[4], short* SBn) {
        u32x4 res;
#pragma unroll
        for (int qd = 0; qd < 4; ++qd) {
            f32x2 a = pk_mul(unpack2(gr[0][qd]), wpair[0]);
            a = pk_fma(unpack2(gr[1][qd]), wpair[1], a);
            a = pk_fma(unpack2(gr[2][qd]), wpair[2], a);
            a = pk_fma(unpack2(gr[3][qd]), wpair[3], a);
            res[qd] = cvt_pk_bf16(a.x, a.y);
        }
        *(u32x4*)&SBn[wr0] = res;
    };

    {
        float2 o0 = offv[(size_t)px * 16];
        SETUP(0, o0.x, o0.y);
        u32x4 g0[4], g1[4];
        GISSUE(0, g0);
        GISSUE(1, g1);
        WLOAD(0, wA[0]);
        WLOAD(1, wA[1]);
        COMBINE_WRITE(g0, &S_s[0][0]);
        COMBINE_WRITE(g1, &S_s[1][0]);
        GISSUE(2, g[0]);
        GISSUE(3, g[1]);
        offn = offv[(size_t)px * 16 + 1];
        asm volatile("s_waitcnt lgkmcnt(0)" ::: "memory");
    }

    auto ITER2 = [&](int s, u32x4 (&wcur)[2][4], u32x4 (&wnxt)[2][4], short* SBc, short* SBn) {
        __builtin_amdgcn_s_barrier();
        __builtin_amdgcn_sched_barrier(0);
        if (s + 2 < NSTEP) {
            COMBINE_WRITE(g[0], SBn);
            COMBINE_WRITE(g[1], SBn + 64 * 64);
        }
        if ((s & 3) == 0 && s + 4 < NSTEP)
            SETUP((s + 4) >> 2, offn.x, offn.y);
        if ((s & 3) == 2 && ((s + 8) >> 2) < 9)
            offn = offv[(size_t)px * 16 + ((s + 8) >> 2)];
        if (s + 4 < NSTEP) {
            GISSUE(s + 4, g[0]);
            GISSUE(s + 5, g[1]);
        }
        if (s + 2 < NSTEP) {
            WLOAD(s + 2, wnxt[0]);
            WLOAD(s + 3, wnxt[1]);
        }
#pragma unroll
        for (int half = 0; half < 2; ++half) {
            const short* SB = SBc + half * 64 * 64;
            short8v sf[4][2];
#pragma unroll
            for (int ni = 0; ni < 4; ++ni) {
                int row = ni * 16 + (lane & 15);
#pragma unroll
                for (int kf = 0; kf < 2; ++kf) {
                    int c8 = kf * 4 + (lane >> 4);
                    sf[ni][kf] = *(const short8v*)&SB[row * 64 + ((c8 ^ (row & 7)) << 3)];
                }
            }
            __builtin_amdgcn_s_setprio(1);
#pragma unroll
            for (int kf = 0; kf < 2; ++kf)
#pragma unroll
                for (int mi = 0; mi < 2; ++mi)
#pragma unroll
                    for (int ni = 0; ni < 4; ++ni)
                        acc[mi][ni] = __builtin_amdgcn_mfma_f32_16x16x32_bf16(
                            __builtin_bit_cast(short8v, wcur[half][kf * 2 + mi]), sf[ni][kf],
                            acc[mi][ni], 0, 0, 0);
            __builtin_amdgcn_s_setprio(0);
        }
        asm volatile("s_waitcnt lgkmcnt(0)" ::: "memory");
    };

    for (int s4 = 0; s4 < NSTEP; s4 += 4) {
        ITER2(s4, wA, wB, &S_s[0][0], &S_s[2][0]);
        ITER2(s4 + 2, wB, wA, &S_s[2][0], &S_s[0][0]);
    }

#pragma unroll
    for (int mi = 0; mi < 2; ++mi) {
        int o = wv * 32 + mi * 16 + (lane >> 4) * 4;
#pragma unroll
        for (int j = 0; j < 4; ++j) {
            size_t rowbase = ((size_t)b * 256 + o + j) * HWp;
#pragma unroll
            for (int ni = 0; ni < 4; ++ni) {
                int p2 = (px0 + ni * 16 + (lane & 15)) & 4095;
                size_t idx = rowbase + p2;
                out[idx] = 0.5f * (xn[idx] + fmaxf(acc[mi][ni][j], 0.f));
            }
        }
    }
}

extern "C" void kernel_launch(void* const* d_in, const int* in_sizes, int n_in,
                              void* d_out, int out_size, void* d_ws, size_t ws_size,
                              hipStream_t stream) {
    const float* x_ref  = (const float*)d_in[0];
    const float* x_next = (const float*)d_in[1];
    const float* w1 = (const float*)d_in[2];
    const float* b1 = (const float*)d_in[3];
    const float* w2 = (const float*)d_in[4];
    const float* b2 = (const float*)d_in[5];
    const float* w3 = (const float*)d_in[6];
    const float* b3 = (const float*)d_in[7];
    const float* wd = (const float*)d_in[8];
    float* out = (float*)d_out;
    char* ws = (char*)d_ws;

    unsigned short* h1h = (unsigned short*)(ws + B_H1H);
    unsigned short* h2h = (unsigned short*)(ws + B_H2H);
    unsigned short* xth = (unsigned short*)(ws + B_XTH);
    float* prod8 = (float*)(ws + B_PROD8);
    float* offp = (float*)(ws + B_OFFP);
    unsigned short* wb2f = (unsigned short*)(ws + B_WB2);
    unsigned short* wbdf = (unsigned short*)(ws + B_WBD);
    unsigned short* wb3f = (unsigned short*)(ws + B_WB3);

    k_initx<<<10552, 256, 0, stream>>>(w2, wd, w3, wb2f, wbdf, wb3f, h1h, h2h, xth,
                                       x_ref, x_next, prod8);
    k_conv1c<<<NPIX / 32, 256, 0, stream>>>(prod8, w1, b1, h1h);
    k_conv2g<<<512, 256, 0, stream>>>(h1h, wb2f, b2, h2h);
    k_conv3g<<<256, 256, 0, stream>>>(h2h, wb3f, b3, offp);
    k_dcng<<<256, 512, 0, stream>>>(xth, offp, wbdf, x_next, out);
}